// Round 8
// baseline (182.279 us; speedup 1.0000x reference)
//
#include <hip/hip_runtime.h>
#include <hip/hip_bf16.h>

// Fused attention fwd: x@Wqkv -> RoPE -> causal flash attn (bf16 MFMA) -> @Wout
// B=2 T=2048 D=1024 H=16 DH=64
#define B_ 2
#define T_ 2048
#define D_ 1024
#define H_ 16
#define DH_ 64
#define N3_ 3072
#define M_ 4096

typedef __attribute__((ext_vector_type(8))) short short8;      // 8 bf16 (4 VGPR) MFMA A/B frag
typedef __attribute__((ext_vector_type(4))) float f32x4;       // MFMA C/D frag
typedef __attribute__((ext_vector_type(4))) unsigned short ushort4v;

// native f32->bf16 (compiler emits hw cvt; RNE) [m240: scalar cast is the fast path]
__device__ __forceinline__ unsigned short f2bf(float f) {
  return __builtin_bit_cast(unsigned short, __hip_bfloat16(f));
}
__device__ __forceinline__ float bf2f(unsigned short u) {
  union { unsigned u; float f; } v; v.u = ((unsigned)u) << 16;
  return v.f;
}

// async global->LDS, 16B per lane; LDS dest is WAVE-UNIFORM base + lane*16 [m97/m104]
__device__ __forceinline__ void gload_lds16(const unsigned short* g, unsigned short* l) {
  __builtin_amdgcn_global_load_lds((const __attribute__((address_space(1))) void*)g,
                                   (__attribute__((address_space(3))) void*)l, 16, 0, 0);
}

// ---------- f32 -> bf16 bulk convert (4 elems/thread, exact grid) ----------
__global__ __launch_bounds__(256)
void k_cvt(const float* __restrict__ in, unsigned short* __restrict__ out) {
  int i = (blockIdx.x * 256 + threadIdx.x) * 4;
  f32x4 v = *(const f32x4*)&in[i];
  ushort4v o;
  o[0] = f2bf(v[0]); o[1] = f2bf(v[1]); o[2] = f2bf(v[2]); o[3] = f2bf(v[3]);
  *(ushort4v*)&out[i] = o;
}

// ---------- transpose f32 [R][C] -> bf16 [C][R] (64x64 LDS tile) ----------
__global__ __launch_bounds__(256)
void k_transpose(const float* __restrict__ in, unsigned short* __restrict__ out,
                 int R, int C) {
  __shared__ float tile[64][65];
  int c0 = blockIdx.x * 64, r0 = blockIdx.y * 64;
  int tx = threadIdx.x & 63, ty = threadIdx.x >> 6;
#pragma unroll
  for (int i = 0; i < 64; i += 4)
    tile[ty + i][tx] = in[(size_t)(r0 + ty + i) * C + c0 + tx];
  __syncthreads();
#pragma unroll
  for (int i = 0; i < 64; i += 4)
    out[(size_t)(c0 + ty + i) * R + r0 + tx] = f2bf(tile[tx][ty + i]);
}

// ---------- GEMM: C[M][N] = A[M][K] @ Bt[N][K]^T, bf16 in, OUT_T out ----------
// 128x128 tile, BK=64, 4 waves (2x2), 4x4 16x16x32 MFMA frags per wave.
// Staging via global_load_lds width=16 (m97 pattern; linear LDS, no swizzle --
// T2 is null on 2-phase 128^2 [m228d/m230]).
template <typename OUT_T>
__global__ __launch_bounds__(256)
void k_gemm_bt(const unsigned short* __restrict__ A, const unsigned short* __restrict__ Bt,
               OUT_T* __restrict__ C, int Mx, int Nx, int Kx) {
  __shared__ __align__(16) unsigned short As[128 * 64];
  __shared__ __align__(16) unsigned short Bs[128 * 64];
  const int tid = threadIdx.x;
  const int lane = tid & 63;
  const int l15 = lane & 15, lg = lane >> 4;
  const int l8 = lane >> 3, c8 = lane & 7;
  const int wid = tid >> 6;
  const int wr = wid >> 1, wc = wid & 1;
  const int m0 = blockIdx.y * 128, n0 = blockIdx.x * 128;

  const f32x4 zero4 = {0.f, 0.f, 0.f, 0.f};
  f32x4 acc[4][4];
#pragma unroll
  for (int mi = 0; mi < 4; ++mi)
#pragma unroll
    for (int ni = 0; ni < 4; ++ni) acc[mi][ni] = zero4;

  for (int k0 = 0; k0 < Kx; k0 += 64) {
    // wave wid stages rows [wid*32, wid*32+32) of As and Bs; 8 rows per call.
#pragma unroll
    for (int i = 0; i < 4; ++i)
      gload_lds16(&A[(size_t)(m0 + wid * 32 + i * 8 + l8) * Kx + k0 + c8 * 8],
                  &As[(wid * 32 + i * 8) * 64]);
#pragma unroll
    for (int i = 0; i < 4; ++i)
      gload_lds16(&Bt[(size_t)(n0 + wid * 32 + i * 8 + l8) * Kx + k0 + c8 * 8],
                  &Bs[(wid * 32 + i * 8) * 64]);
    __syncthreads();                     // compiler drains vmcnt before barrier
#pragma unroll
    for (int kk = 0; kk < 2; ++kk) {
      short8 af[4], bfr[4];
#pragma unroll
      for (int mi = 0; mi < 4; ++mi)
        af[mi] = *(const short8*)&As[(wr * 64 + mi * 16 + l15) * 64 + kk * 32 + lg * 8];
#pragma unroll
      for (int ni = 0; ni < 4; ++ni)
        bfr[ni] = *(const short8*)&Bs[(wc * 64 + ni * 16 + l15) * 64 + kk * 32 + lg * 8];
#pragma unroll
      for (int mi = 0; mi < 4; ++mi)
#pragma unroll
        for (int ni = 0; ni < 4; ++ni)
          acc[mi][ni] = __builtin_amdgcn_mfma_f32_16x16x32_bf16(af[mi], bfr[ni], acc[mi][ni], 0, 0, 0);
    }
    __syncthreads();
  }
  // C/D layout: reg j -> row (lg*4+j), col l15  [verified m89/m91]
#pragma unroll
  for (int mi = 0; mi < 4; ++mi)
#pragma unroll
    for (int ni = 0; ni < 4; ++ni)
#pragma unroll
      for (int j = 0; j < 4; ++j) {
        int row = m0 + wr * 64 + mi * 16 + lg * 4 + j;
        int col = n0 + wc * 64 + ni * 16 + l15;
        float v = acc[mi][ni][j];
        if constexpr (sizeof(OUT_T) == 2) C[(size_t)row * Nx + col] = f2bf(v);
        else                              C[(size_t)row * Nx + col] = v;
      }
}

// ---------- RoPE + layout: qkv[4096][3072] -> Q,K [BH][T][DH] (Q pre-scaled 1/8), V^T [BH][DH][T] ----------
__global__ __launch_bounds__(256)
void k_rope(const unsigned short* __restrict__ qkv, const float* __restrict__ cosT,
            const float* __restrict__ sinT, unsigned short* __restrict__ Q,
            unsigned short* __restrict__ K, unsigned short* __restrict__ Vt) {
  int idx = blockIdx.x * 256 + threadIdx.x;        // B*H*T*32 threads
  int dh = idx & 31;
  int t  = (idx >> 5) & (T_ - 1);
  int h  = (idx >> 16) & (H_ - 1);
  int b  = idx >> 20;
  size_t base = (size_t)(b * T_ + t) * N3_;
  int c0 = h * DH_ + dh;
  float q1 = bf2f(qkv[base + c0]);
  float q2 = bf2f(qkv[base + c0 + 32]);
  float k1 = bf2f(qkv[base + D_ + c0]);
  float k2 = bf2f(qkv[base + D_ + c0 + 32]);
  float cs = cosT[t * 32 + dh], sn = sinT[t * 32 + dh];
  size_t qkb = ((size_t)(b * H_ + h) * T_ + t) * DH_ + dh;
  Q[qkb]      = f2bf((q1 * cs - q2 * sn) * 0.125f);   // attn scale folded into Q
  Q[qkb + 32] = f2bf((q2 * cs + q1 * sn) * 0.125f);
  K[qkb]      = f2bf(k1 * cs - k2 * sn);
  K[qkb + 32] = f2bf(k2 * cs + k1 * sn);
  size_t vb = ((size_t)(b * H_ + h) * DH_ + dh) * T_ + t;
  Vt[vb]           = qkv[base + 2 * D_ + c0];
  Vt[vb + 32 * T_] = qkv[base + 2 * D_ + c0 + 32];
}

// ---------- causal flash attention (block-cooperative, LDS-staged KV) ----------
// Block = 4 waves x 32 q-rows = 128 q-rows. Each wave: two 16-row q-groups that
// SHARE every K/V LDS fragment (2x MFMA per ds_read/stage/barrier). KV loop in
// 64-key tiles, double-buffered gload_lds staging (linear dest + pre-swizzled
// global source; reads XOR back). One softmax round per 64 keys per group;
// defer-max (T13, THR=8). XCD-chunked swizzle: 4 heads/XCD -> K/V L2-resident.
__global__ __launch_bounds__(256)
void k_attn(const unsigned short* __restrict__ Q, const unsigned short* __restrict__ K,
            const unsigned short* __restrict__ Vt, unsigned short* __restrict__ O) {
  __shared__ __align__(16) unsigned short Ks[2 * 64 * 64];   // [buf][r][chunk^(r&7)] 8KB/buf
  __shared__ __align__(16) unsigned short Vs[2 * 64 * 64];   // same, rows = dh
  __shared__ __align__(16) unsigned short Pl[4][32][72];     // per-wave P (2 groups x 16 rows)
  const int tid = threadIdx.x;
  const int wid = tid >> 6, lane = tid & 63;
  const int l15 = lane & 15, lg = lane >> 4;
  const int l8 = lane >> 3, c8 = lane & 7;
  const int srcoff = (c8 ^ l8) << 3;          // swizzled source chunk (ushort units)
  // XCD-chunked bijective swizzle (nwg=512 divisible by 8): 64 blocks/XCD = 4 heads
  // = 2MB K/V per XCD L2.
  const int wg = (blockIdx.x & 7) * 64 + (blockIdx.x >> 3);
  const int qb = 15 - (wg & 15);              // reversed: longest jobs first
  const int hb = wg >> 4;                     // b*H + h
  const int qblk = qb * 128;
  const int q0 = qblk + wid * 32;
  const size_t hbase = (size_t)hb * T_ * DH_;
  const unsigned short* Qh = Q + hbase;
  const unsigned short* Kh = K + hbase;
  const unsigned short* Vh = Vt + hbase;      // [DH][T]
  unsigned short* Pw = &Pl[wid][0][0];

  // Q^T B-frags for both 16-row groups (rows q0+l15 and q0+16+l15)
  short8 bq0g0 = *(const short8*)&Qh[(q0 + l15) * DH_ + lg * 8];
  short8 bq1g0 = *(const short8*)&Qh[(q0 + l15) * DH_ + 32 + lg * 8];
  short8 bq0g1 = *(const short8*)&Qh[(q0 + 16 + l15) * DH_ + lg * 8];
  short8 bq1g1 = *(const short8*)&Qh[(q0 + 16 + l15) * DH_ + 32 + lg * 8];

  // hoisted swizzled LDS read offsets (kt-invariant)
  int koffA[4], koffB[4], voff[2][4];
#pragma unroll
  for (int g = 0; g < 4; ++g) {
    int r = g * 16 + l15;
    koffA[g] = r * 64 + (((lg)     ^ (r & 7)) << 3);
    koffB[g] = r * 64 + (((4 + lg) ^ (r & 7)) << 3);
  }
#pragma unroll
  for (int ks = 0; ks < 2; ++ks)
#pragma unroll
    for (int nb = 0; nb < 4; ++nb) {
      int r = nb * 16 + l15;
      voff[ks][nb] = r * 64 + (((ks * 4 + lg) ^ (r & 7)) << 3);
    }

  const f32x4 zero4 = {0.f, 0.f, 0.f, 0.f};
  f32x4 accO0[4], accO1[4];
#pragma unroll
  for (int nb = 0; nb < 4; ++nb) { accO0[nb] = zero4; accO1[nb] = zero4; }
  float m0r = -INFINITY, l0r = 0.f, m1r = -INFINITY, l1r = 0.f;
  const int qg0 = q0 + l15, qg1 = q0 + 16 + l15;
  const int kend_w = q0 + 32;                 // wave's exclusive key bound
  const int kend_blk = qblk + 128;            // block's exclusive key bound

  // stage one 64-key K+V tile: LDS[r][c] = X[r][c^(r&7)] (both-sides swizzle)
  auto stage = [&](int buf, int kt) {
    if (wid < 2) {
      const unsigned short* Kt = Kh + (size_t)kt * DH_;
#pragma unroll
      for (int i = 0; i < 4; ++i)
        gload_lds16(&Kt[(wid * 32 + i * 8 + l8) * DH_ + srcoff],
                    &Ks[buf * 4096 + (wid * 4 + i) * 512]);
    } else {
      const unsigned short* Vg = Vh + kt;
#pragma unroll
      for (int i = 0; i < 4; ++i)
        gload_lds16(&Vg[((wid - 2) * 32 + i * 8 + l8) * T_ + srcoff],
                    &Vs[buf * 4096 + ((wid - 2) * 4 + i) * 512]);
    }
  };

  // per-group softmax on cg[4] -> P rows [prow..prow+15], updates (m_run,l_run,accO)
  auto softmax_group = [&](f32x4* cg, float& m_run, float& l_run, f32x4* accO,
                           int qg, int prow, int kt) {
    float s[16];
#pragma unroll
    for (int g = 0; g < 4; ++g)
#pragma unroll
      for (int j = 0; j < 4; ++j) s[g * 4 + j] = cg[g][j];
    if (kt + 63 > q0) {                       // boundary tile: causal mask
#pragma unroll
      for (int g = 0; g < 4; ++g) {
        int kb0 = kt + g * 16 + lg * 4;
#pragma unroll
        for (int j = 0; j < 4; ++j)
          if (kb0 + j > qg) s[g * 4 + j] = -INFINITY;
      }
    }
    // tree max (depth 4)
    float t8[8];
#pragma unroll
    for (int j = 0; j < 8; ++j) t8[j] = fmaxf(s[j], s[j + 8]);
    float pm = fmaxf(fmaxf(fmaxf(t8[0], t8[4]), fmaxf(t8[1], t8[5])),
                     fmaxf(fmaxf(t8[2], t8[6]), fmaxf(t8[3], t8[7])));
    pm = fmaxf(pm, __shfl_xor(pm, 16));
    pm = fmaxf(pm, __shfl_xor(pm, 32));
    // defer-max [T13]: only rescale when the running max grew by > 8
    if (!__all(pm <= m_run + 8.f)) {
      float m_new = fmaxf(m_run, pm);
      float alpha = __expf(m_run - m_new);    // first tile: exp(-inf)=0
      float aj[4];
#pragma unroll
      for (int j = 0; j < 4; ++j) aj[j] = __shfl(alpha, lg * 4 + j);
#pragma unroll
      for (int nb = 0; nb < 4; ++nb)
#pragma unroll
        for (int j = 0; j < 4; ++j) accO[nb][j] *= aj[j];
      l_run *= alpha;
      m_run = m_new;
    }
    float p[16];
#pragma unroll
    for (int j = 0; j < 16; ++j) p[j] = __expf(s[j] - m_run);
    // tree sum
    float u8[8];
#pragma unroll
    for (int j = 0; j < 8; ++j) u8[j] = p[j] + p[j + 8];
    float psum = ((u8[0] + u8[4]) + (u8[1] + u8[5])) + ((u8[2] + u8[6]) + (u8[3] + u8[7]));
    psum += __shfl_xor(psum, 16);
    psum += __shfl_xor(psum, 32);
    l_run += psum;
    // P -> LDS (bf16), 4x 8B stores at P[prow+l15][g*16+lg*4]
#pragma unroll
    for (int g = 0; g < 4; ++g) {
      ushort4v pk;
#pragma unroll
      for (int j = 0; j < 4; ++j) pk[j] = f2bf(p[g * 4 + j]);
      *(ushort4v*)&Pw[(prow + l15) * 72 + g * 16 + lg * 4] = pk;
    }
  };

  stage(0, 0);
  for (int kt = 0; kt < kend_blk; kt += 64) {
    const int cur = (kt >> 6) & 1;
    __syncthreads();                          // staging of cur landed; cur^1 free
    if (kt + 64 < kend_blk) stage(cur ^ 1, kt + 64);
    if (kt >= kend_w) continue;               // wave-uniform; keeps hitting barrier
    const unsigned short* Kb_ = &Ks[cur * 4096];
    const unsigned short* Vb_ = &Vs[cur * 4096];

    // S^T: 4 k-groups of 16 rows; K frags SHARED by both q-groups
    f32x4 cg0[4], cg1[4];
#pragma unroll
    for (int g = 0; g < 4; ++g) {
      short8 a0 = *(const short8*)&Kb_[koffA[g]];
      short8 a1 = *(const short8*)&Kb_[koffB[g]];
      cg0[g] = __builtin_amdgcn_mfma_f32_16x16x32_bf16(a0, bq0g0, zero4, 0, 0, 0);
      cg0[g] = __builtin_amdgcn_mfma_f32_16x16x32_bf16(a1, bq1g0, cg0[g], 0, 0, 0);
      cg1[g] = __builtin_amdgcn_mfma_f32_16x16x32_bf16(a0, bq0g1, zero4, 0, 0, 0);
      cg1[g] = __builtin_amdgcn_mfma_f32_16x16x32_bf16(a1, bq1g1, cg1[g], 0, 0, 0);
    }
    softmax_group(cg0, m0r, l0r, accO0, qg0, 0, kt);
    softmax_group(cg1, m1r, l1r, accO1, qg1, 16, kt);

    // PV: P frags per group, V frags SHARED
#pragma unroll
    for (int ks = 0; ks < 2; ++ks) {
      short8 pa0 = *(const short8*)&Pw[l15 * 72 + ks * 32 + lg * 8];
      short8 pa1 = *(const short8*)&Pw[(16 + l15) * 72 + ks * 32 + lg * 8];
#pragma unroll
      for (int nb = 0; nb < 4; ++nb) {
        short8 vb = *(const short8*)&Vb_[voff[ks][nb]];
        accO0[nb] = __builtin_amdgcn_mfma_f32_16x16x32_bf16(pa0, vb, accO0[nb], 0, 0, 0);
        accO1[nb] = __builtin_amdgcn_mfma_f32_16x16x32_bf16(pa1, vb, accO1[nb], 0, 0, 0);
      }
    }
  }
  // epilogue: /l, write O[(b*T+t)][h*64+dh] bf16 for both groups
  float lj0[4], lj1[4];
#pragma unroll
  for (int j = 0; j < 4; ++j) {
    lj0[j] = 1.f / __shfl(l0r, lg * 4 + j);
    lj1[j] = 1.f / __shfl(l1r, lg * 4 + j);
  }
  int b = hb >> 4, h = hb & 15;
#pragma unroll
  for (int nb = 0; nb < 4; ++nb)
#pragma unroll
    for (int j = 0; j < 4; ++j) {
      int t0 = q0 + lg * 4 + j;
      O[(size_t)(b * T_ + t0) * D_ + h * DH_ + nb * 16 + l15] = f2bf(accO0[nb][j] * lj0[j]);
      int t1 = q0 + 16 + lg * 4 + j;
      O[(size_t)(b * T_ + t1) * D_ + h * DH_ + nb * 16 + l15] = f2bf(accO1[nb][j] * lj1[j]);
    }
}

extern "C" void kernel_launch(void* const* d_in, const int* in_sizes, int n_in,
                              void* d_out, int out_size, void* d_ws, size_t ws_size,
                              hipStream_t stream) {
  const float* x    = (const float*)d_in[0];
  const float* Wqkv = (const float*)d_in[1];
  const float* Wout = (const float*)d_in[2];
  const float* cosT = (const float*)d_in[3];
  const float* sinT = (const float*)d_in[4];
  // d_in[5] = mask (unused; causal handled analytically)
  float* out = (float*)d_out;
  char* ws = (char*)d_ws;
  // ws layout (bytes): 64 MB total
  unsigned short* Xb     = (unsigned short*)(ws);              //  8.0 MB  x bf16 [4096][1024]
  unsigned short* Wqkv_t = (unsigned short*)(ws + 8388608);    //  6.0 MB  Wqkv^T bf16 [3072][1024]
  unsigned short* Wout_t = (unsigned short*)(ws + 14680064);   //  2.0 MB  Wout^T bf16 [1024][1024]
  unsigned short* QKVb   = (unsigned short*)(ws + 16777216);   // 24.0 MB  qkv bf16 [4096][3072]
  unsigned short* Qb     = (unsigned short*)(ws + 41943040);   //  8.0 MB  [BH][T][DH]
  unsigned short* Kb     = (unsigned short*)(ws + 50331648);   //  8.0 MB  [BH][T][DH]
  unsigned short* Vt     = (unsigned short*)(ws + 58720256);   //  8.0 MB  [BH][DH][T]
  unsigned short* Ob     = QKVb;                               // reuse (qkv dead after rope)

  k_cvt<<<4096, 256, 0, stream>>>(x, Xb);
  k_transpose<<<dim3(48, 16), 256, 0, stream>>>(Wqkv, Wqkv_t, 1024, 3072);
  k_transpose<<<dim3(16, 16), 256, 0, stream>>>(Wout, Wout_t, 1024, 1024);
  k_gemm_bt<unsigned short><<<dim3(24, 32), 256, 0, stream>>>(Xb, Wqkv_t, QKVb, 4096, 3072, 1024);
  k_rope<<<8192, 256, 0, stream>>>(QKVb, cosT, sinT, Qb, Kb, Vt);
  k_attn<<<512, 256, 0, stream>>>(Qb, Kb, Vt, Ob);
  k_gemm_bt<float><<<dim3(8, 32), 256, 0, stream>>>(Ob, Wout_t, out, 4096, 1024, 1024);
}

// Round 9
// 149.790 us; speedup vs baseline: 1.2169x; 1.2169x over previous
//
#include <hip/hip_runtime.h>
#include <hip/hip_bf16.h>

// Fused attention fwd: x@Wqkv(+RoPE fused) -> causal flash attn (bf16 MFMA) -> @Wout
// B=2 T=2048 D=1024 H=16 DH=64
#define B_ 2
#define T_ 2048
#define D_ 1024
#define H_ 16
#define DH_ 64
#define N3_ 3072
#define M_ 4096

typedef __attribute__((ext_vector_type(8))) short short8;      // 8 bf16 (4 VGPR) MFMA A/B frag
typedef __attribute__((ext_vector_type(4))) float f32x4;       // MFMA C/D frag
typedef __attribute__((ext_vector_type(4))) unsigned short ushort4v;

// native f32->bf16 (compiler emits hw cvt; RNE) [m240: scalar cast is the fast path]
__device__ __forceinline__ unsigned short f2bf(float f) {
  return __builtin_bit_cast(unsigned short, __hip_bfloat16(f));
}
__device__ __forceinline__ float bf2f(unsigned short u) {
  union { unsigned u; float f; } v; v.u = ((unsigned)u) << 16;
  return v.f;
}

// async global->LDS, 16B per lane; LDS dest is WAVE-UNIFORM base + lane*16 [m97/m104]
__device__ __forceinline__ void gload_lds16(const unsigned short* g, unsigned short* l) {
  __builtin_amdgcn_global_load_lds((const __attribute__((address_space(1))) void*)g,
                                   (__attribute__((address_space(3))) void*)l, 16, 0, 0);
}

// ---------- f32 -> bf16 bulk convert (4 elems/thread, exact grid) ----------
__global__ __launch_bounds__(256)
void k_cvt(const float* __restrict__ in, unsigned short* __restrict__ out) {
  int i = (blockIdx.x * 256 + threadIdx.x) * 4;
  f32x4 v = *(const f32x4*)&in[i];
  ushort4v o;
  o[0] = f2bf(v[0]); o[1] = f2bf(v[1]); o[2] = f2bf(v[2]); o[3] = f2bf(v[3]);
  *(ushort4v*)&out[i] = o;
}

// ---------- transpose f32 [R][C] -> bf16 [C][R] (64x64 LDS tile) ----------
__global__ __launch_bounds__(256)
void k_transpose(const float* __restrict__ in, unsigned short* __restrict__ out,
                 int R, int C) {
  __shared__ float tile[64][65];
  int c0 = blockIdx.x * 64, r0 = blockIdx.y * 64;
  int tx = threadIdx.x & 63, ty = threadIdx.x >> 6;
#pragma unroll
  for (int i = 0; i < 64; i += 4)
    tile[ty + i][tx] = in[(size_t)(r0 + ty + i) * C + c0 + tx];
  __syncthreads();
#pragma unroll
  for (int i = 0; i < 64; i += 4)
    out[(size_t)(c0 + ty + i) * R + r0 + tx] = f2bf(tile[tx][ty + i]);
}

// ---------- GEMM: C[M][N] = A[M][K] @ Bt[N][K]^T, bf16 in, OUT_T out ----------
// 128x128 tile, BK=64, 4 waves (2x2), 4x4 16x16x32 MFMA frags per wave.
// Staging via global_load_lds width=16 (m97 pattern; linear LDS, no swizzle).
template <typename OUT_T>
__global__ __launch_bounds__(256)
void k_gemm_bt(const unsigned short* __restrict__ A, const unsigned short* __restrict__ Bt,
               OUT_T* __restrict__ C, int Mx, int Nx, int Kx) {
  __shared__ __align__(16) unsigned short As[128 * 64];
  __shared__ __align__(16) unsigned short Bs[128 * 64];
  const int tid = threadIdx.x;
  const int lane = tid & 63;
  const int l15 = lane & 15, lg = lane >> 4;
  const int l8 = lane >> 3, c8 = lane & 7;
  const int wid = tid >> 6;
  const int wr = wid >> 1, wc = wid & 1;
  const int m0 = blockIdx.y * 128, n0 = blockIdx.x * 128;

  const f32x4 zero4 = {0.f, 0.f, 0.f, 0.f};
  f32x4 acc[4][4];
#pragma unroll
  for (int mi = 0; mi < 4; ++mi)
#pragma unroll
    for (int ni = 0; ni < 4; ++ni) acc[mi][ni] = zero4;

  for (int k0 = 0; k0 < Kx; k0 += 64) {
#pragma unroll
    for (int i = 0; i < 4; ++i)
      gload_lds16(&A[(size_t)(m0 + wid * 32 + i * 8 + l8) * Kx + k0 + c8 * 8],
                  &As[(wid * 32 + i * 8) * 64]);
#pragma unroll
    for (int i = 0; i < 4; ++i)
      gload_lds16(&Bt[(size_t)(n0 + wid * 32 + i * 8 + l8) * Kx + k0 + c8 * 8],
                  &Bs[(wid * 32 + i * 8) * 64]);
    __syncthreads();
#pragma unroll
    for (int kk = 0; kk < 2; ++kk) {
      short8 af[4], bfr[4];
#pragma unroll
      for (int mi = 0; mi < 4; ++mi)
        af[mi] = *(const short8*)&As[(wr * 64 + mi * 16 + l15) * 64 + kk * 32 + lg * 8];
#pragma unroll
      for (int ni = 0; ni < 4; ++ni)
        bfr[ni] = *(const short8*)&Bs[(wc * 64 + ni * 16 + l15) * 64 + kk * 32 + lg * 8];
#pragma unroll
      for (int mi = 0; mi < 4; ++mi)
#pragma unroll
        for (int ni = 0; ni < 4; ++ni)
          acc[mi][ni] = __builtin_amdgcn_mfma_f32_16x16x32_bf16(af[mi], bfr[ni], acc[mi][ni], 0, 0, 0);
    }
    __syncthreads();
  }
  // C/D layout: reg j -> row (lg*4+j), col l15  [verified m89/m91]
#pragma unroll
  for (int mi = 0; mi < 4; ++mi)
#pragma unroll
    for (int ni = 0; ni < 4; ++ni)
#pragma unroll
      for (int j = 0; j < 4; ++j) {
        int row = m0 + wr * 64 + mi * 16 + lg * 4 + j;
        int col = n0 + wc * 64 + ni * 16 + l15;
        float v = acc[mi][ni][j];
        if constexpr (sizeof(OUT_T) == 2) C[(size_t)row * Nx + col] = f2bf(v);
        else                              C[(size_t)row * Nx + col] = v;
      }
}

// ---------- fused QKV GEMM + RoPE + layout ----------
// C = Xb[4096][1024] @ Wqkv_t^T -> per-region epilogue:
//   cols [0,1024):   Q rope + 1/8 scale -> Q [BH][T][DH]
//   cols [1024,2048): K rope            -> K [BH][T][DH]
//   cols [2048,3072): V passthrough      -> Vt [BH][DH][T]
// RoPE pair (dh, dh+32) = (acc[mi][ni], acc[mi][ni+2]) for ni in {0,1} — in-register.
__global__ __launch_bounds__(256)
void k_gemm_qkv_rope(const unsigned short* __restrict__ A, const unsigned short* __restrict__ Bt,
                     const float* __restrict__ cosT, const float* __restrict__ sinT,
                     unsigned short* __restrict__ Q, unsigned short* __restrict__ K,
                     unsigned short* __restrict__ Vt) {
  __shared__ __align__(16) unsigned short As[128 * 64];
  __shared__ __align__(16) unsigned short Bs[128 * 64];
  const int Kx = D_, Nx = N3_;
  const int tid = threadIdx.x;
  const int lane = tid & 63;
  const int l15 = lane & 15, lg = lane >> 4;
  const int l8 = lane >> 3, c8 = lane & 7;
  const int wid = tid >> 6;
  const int wr = wid >> 1, wc = wid & 1;
  const int m0 = blockIdx.y * 128, n0 = blockIdx.x * 128;

  const f32x4 zero4 = {0.f, 0.f, 0.f, 0.f};
  f32x4 acc[4][4];
#pragma unroll
  for (int mi = 0; mi < 4; ++mi)
#pragma unroll
    for (int ni = 0; ni < 4; ++ni) acc[mi][ni] = zero4;

  for (int k0 = 0; k0 < Kx; k0 += 64) {
#pragma unroll
    for (int i = 0; i < 4; ++i)
      gload_lds16(&A[(size_t)(m0 + wid * 32 + i * 8 + l8) * Kx + k0 + c8 * 8],
                  &As[(wid * 32 + i * 8) * 64]);
#pragma unroll
    for (int i = 0; i < 4; ++i)
      gload_lds16(&Bt[(size_t)(n0 + wid * 32 + i * 8 + l8) * Kx + k0 + c8 * 8],
                  &Bs[(wid * 32 + i * 8) * 64]);
    __syncthreads();
#pragma unroll
    for (int kk = 0; kk < 2; ++kk) {
      short8 af[4], bfr[4];
#pragma unroll
      for (int mi = 0; mi < 4; ++mi)
        af[mi] = *(const short8*)&As[(wr * 64 + mi * 16 + l15) * 64 + kk * 32 + lg * 8];
#pragma unroll
      for (int ni = 0; ni < 4; ++ni)
        bfr[ni] = *(const short8*)&Bs[(wc * 64 + ni * 16 + l15) * 64 + kk * 32 + lg * 8];
#pragma unroll
      for (int mi = 0; mi < 4; ++mi)
#pragma unroll
        for (int ni = 0; ni < 4; ++ni)
          acc[mi][ni] = __builtin_amdgcn_mfma_f32_16x16x32_bf16(af[mi], bfr[ni], acc[mi][ni], 0, 0, 0);
    }
    __syncthreads();
  }

  const int region = n0 >> 10;                 // 0=Q 1=K 2=V (tile-aligned boundaries)
  const int h = (((n0 & 1023)) + wc * 64) >> 6;   // head of this wave's 64-col block
  if (region < 2) {
    unsigned short* out = (region == 0) ? Q : K;
    const float scale = (region == 0) ? 0.125f : 1.f;   // attn 1/sqrt(64) folded into Q
#pragma unroll
    for (int mi = 0; mi < 4; ++mi)
#pragma unroll
      for (int j = 0; j < 4; ++j) {
        int row = m0 + wr * 64 + mi * 16 + lg * 4 + j;
        int b = row >> 11, t = row & (T_ - 1);
        size_t obase = ((size_t)(b * H_ + h) * T_ + t) * DH_;
#pragma unroll
        for (int ni = 0; ni < 2; ++ni) {
          int dh = ni * 16 + l15;              // 0..31
          float cs = cosT[t * 32 + dh], sn = sinT[t * 32 + dh];
          float x1 = acc[mi][ni][j], x2 = acc[mi][ni + 2][j];
          out[obase + dh]      = f2bf((x1 * cs - x2 * sn) * scale);
          out[obase + dh + 32] = f2bf((x2 * cs + x1 * sn) * scale);
        }
      }
  } else {
#pragma unroll
    for (int mi = 0; mi < 4; ++mi) {
      int row0 = m0 + wr * 64 + mi * 16 + lg * 4;
      int b = row0 >> 11, t0 = row0 & (T_ - 1);
#pragma unroll
      for (int ni = 0; ni < 4; ++ni) {
        int col = (n0 - 2048) + wc * 64 + ni * 16 + l15;   // 0..1023
        int hv = col >> 6, dh = col & 63;
        ushort4v pk;
#pragma unroll
        for (int j = 0; j < 4; ++j) pk[j] = f2bf(acc[mi][ni][j]);
        *(ushort4v*)&Vt[((size_t)(b * H_ + hv) * DH_ + dh) * T_ + t0] = pk;
      }
    }
  }
}

// ---------- causal flash attention (block-cooperative, LDS-staged KV) ----------
// [R6 benched version: 59.5 us] Block = 4 waves x 16 q-rows. KV loop in 64-key
// tiles, double-buffered gload_lds staging (linear dest + pre-swizzled global
// source; reads XOR back). One softmax round per 64 keys; defer-max (T13, THR=8).
// XCD-chunked swizzle: 4 heads/XCD -> K/V L2-resident. Grid 1024 (3-4 blocks/CU;
// R7 showed halving the grid costs more in TLP than amortization gains).
__global__ __launch_bounds__(256)
void k_attn(const unsigned short* __restrict__ Q, const unsigned short* __restrict__ K,
            const unsigned short* __restrict__ Vt, unsigned short* __restrict__ O) {
  __shared__ __align__(16) unsigned short Ks[2 * 64 * 64];   // [buf][r][chunk^(r&7)] 8KB/buf
  __shared__ __align__(16) unsigned short Vs[2 * 64 * 64];   // same, rows = dh
  __shared__ __align__(16) unsigned short Pl[4][16][72];     // per-wave P tile (64 + pad 8)
  const int tid = threadIdx.x;
  const int wid = tid >> 6, lane = tid & 63;
  const int l15 = lane & 15, lg = lane >> 4;
  const int l8 = lane >> 3, c8 = lane & 7;
  const int srcoff = (c8 ^ l8) << 3;          // swizzled source chunk (ushort units)
  // XCD-chunked bijective swizzle (nwg=1024): 128 blocks/XCD = 4 heads = 2MB K/V in L2.
  const int wg = (blockIdx.x & 7) * 128 + (blockIdx.x >> 3);
  const int qb = 31 - (wg & 31);              // reversed: longest jobs first
  const int hb = wg >> 5;                     // b*H + h
  const int qblk = qb * 64;
  const int q0 = qblk + wid * 16;
  const size_t hbase = (size_t)hb * T_ * DH_;
  const unsigned short* Qh = Q + hbase;
  const unsigned short* Kh = K + hbase;
  const unsigned short* Vh = Vt + hbase;      // [DH][T]
  unsigned short* Pw = &Pl[wid][0][0];

  // Q^T B-frags, hoisted (b[i] = Q[q0+l15][kk*32+lg*8+i])
  short8 bq0 = *(const short8*)&Qh[(q0 + l15) * DH_ + lg * 8];
  short8 bq1 = *(const short8*)&Qh[(q0 + l15) * DH_ + 32 + lg * 8];

  // hoisted swizzled LDS read offsets (kt-invariant; unrolled-const indexed)
  int koffA[4], koffB[4], voff[2][4];
#pragma unroll
  for (int g = 0; g < 4; ++g) {
    int r = g * 16 + l15;
    koffA[g] = r * 64 + (((lg)     ^ (r & 7)) << 3);
    koffB[g] = r * 64 + (((4 + lg) ^ (r & 7)) << 3);
  }
#pragma unroll
  for (int ks = 0; ks < 2; ++ks)
#pragma unroll
    for (int nb = 0; nb < 4; ++nb) {
      int r = nb * 16 + l15;
      voff[ks][nb] = r * 64 + (((ks * 4 + lg) ^ (r & 7)) << 3);
    }

  const f32x4 zero4 = {0.f, 0.f, 0.f, 0.f};
  f32x4 accO[4];
#pragma unroll
  for (int nb = 0; nb < 4; ++nb) accO[nb] = zero4;
  float m_run = -INFINITY, l_run = 0.f;
  const int qg = q0 + l15;
  const int kend_w = q0 + 16;                 // wave's exclusive key bound
  const int kend_blk = qblk + 64;             // block's exclusive key bound

  // stage one 64-key K+V tile: LDS[r][c] = X[r][c^(r&7)] (both-sides swizzle)
  auto stage = [&](int buf, int kt) {
    if (wid < 2) {
      const unsigned short* Kt = Kh + (size_t)kt * DH_;
#pragma unroll
      for (int i = 0; i < 4; ++i)
        gload_lds16(&Kt[(wid * 32 + i * 8 + l8) * DH_ + srcoff],
                    &Ks[buf * 4096 + (wid * 4 + i) * 512]);
    } else {
      const unsigned short* Vg = Vh + kt;
#pragma unroll
      for (int i = 0; i < 4; ++i)
        gload_lds16(&Vg[((wid - 2) * 32 + i * 8 + l8) * T_ + srcoff],
                    &Vs[buf * 4096 + ((wid - 2) * 4 + i) * 512]);
    }
  };

  stage(0, 0);
  for (int kt = 0; kt < kend_blk; kt += 64) {
    const int cur = (kt >> 6) & 1;
    __syncthreads();                          // staging of cur landed; cur^1 free
    if (kt + 64 < kend_blk) stage(cur ^ 1, kt + 64);
    if (kt >= kend_w) continue;               // wave-uniform; keeps hitting barrier
    const unsigned short* Kb_ = &Ks[cur * 4096];
    const unsigned short* Vb_ = &Vs[cur * 4096];

    // S^T: 4 k-groups of 16 rows; lane holds S[q=q0+l15][k=kt+g*16+lg*4+j]
    f32x4 cg[4];
#pragma unroll
    for (int g = 0; g < 4; ++g) {
      short8 a0 = *(const short8*)&Kb_[koffA[g]];
      short8 a1 = *(const short8*)&Kb_[koffB[g]];
      cg[g] = __builtin_amdgcn_mfma_f32_16x16x32_bf16(a0, bq0, zero4, 0, 0, 0);
      cg[g] = __builtin_amdgcn_mfma_f32_16x16x32_bf16(a1, bq1, cg[g], 0, 0, 0);
    }
    float s[16];
#pragma unroll
    for (int g = 0; g < 4; ++g)
#pragma unroll
      for (int j = 0; j < 4; ++j) s[g * 4 + j] = cg[g][j];
    if (kt + 63 > q0) {                       // boundary tile: causal mask
#pragma unroll
      for (int g = 0; g < 4; ++g) {
        int kb0 = kt + g * 16 + lg * 4;
#pragma unroll
        for (int j = 0; j < 4; ++j)
          if (kb0 + j > qg) s[g * 4 + j] = -INFINITY;
      }
    }
    // tree max (depth 4, not 15-deep chain)
    float t8[8];
#pragma unroll
    for (int j = 0; j < 8; ++j) t8[j] = fmaxf(s[j], s[j + 8]);
    float t4a = fmaxf(t8[0], t8[4]), t4b = fmaxf(t8[1], t8[5]);
    float t4c = fmaxf(t8[2], t8[6]), t4d = fmaxf(t8[3], t8[7]);
    float pm = fmaxf(fmaxf(t4a, t4b), fmaxf(t4c, t4d));
    pm = fmaxf(pm, __shfl_xor(pm, 16));
    pm = fmaxf(pm, __shfl_xor(pm, 32));
    // defer-max [T13]: only rescale when the running max grew by > 8
    if (!__all(pm <= m_run + 8.f)) {
      float m_new = fmaxf(m_run, pm);
      float alpha = __expf(m_run - m_new);    // first tile: exp(-inf)=0
      float aj[4];
#pragma unroll
      for (int j = 0; j < 4; ++j) aj[j] = __shfl(alpha, lg * 4 + j);
#pragma unroll
      for (int nb = 0; nb < 4; ++nb)
#pragma unroll
        for (int j = 0; j < 4; ++j) accO[nb][j] *= aj[j];
      l_run *= alpha;
      m_run = m_new;
    }
    float p[16];
#pragma unroll
    for (int j = 0; j < 16; ++j) p[j] = __expf(s[j] - m_run);
    // tree sum
    float u8[8];
#pragma unroll
    for (int j = 0; j < 8; ++j) u8[j] = p[j] + p[j + 8];
    float u4a = u8[0] + u8[4], u4b = u8[1] + u8[5];
    float u4c = u8[2] + u8[6], u4d = u8[3] + u8[7];
    float psum = (u4a + u4b) + (u4c + u4d);
    psum += __shfl_xor(psum, 16);
    psum += __shfl_xor(psum, 32);
    l_run += psum;

    // P -> LDS (bf16), 4x 8B stores at P[q=l15][g*16+lg*4]
#pragma unroll
    for (int g = 0; g < 4; ++g) {
      ushort4v pk;
#pragma unroll
      for (int j = 0; j < 4; ++j) pk[j] = f2bf(p[g * 4 + j]);
      *(ushort4v*)&Pw[l15 * 72 + g * 16 + lg * 4] = pk;
    }
    // PV: A-frag from LDS P, B-frag from swizzled V tile (rows = dh)
#pragma unroll
    for (int ks = 0; ks < 2; ++ks) {
      short8 pa = *(const short8*)&Pw[l15 * 72 + ks * 32 + lg * 8];
#pragma unroll
      for (int nb = 0; nb < 4; ++nb) {
        short8 vb = *(const short8*)&Vb_[voff[ks][nb]];
        accO[nb] = __builtin_amdgcn_mfma_f32_16x16x32_bf16(pa, vb, accO[nb], 0, 0, 0);
      }
    }
  }
  // epilogue: /l, write O[(b*T+t)][h*64+dh] bf16
  float lj[4];
#pragma unroll
  for (int j = 0; j < 4; ++j) lj[j] = 1.f / __shfl(l_run, lg * 4 + j);
  int b = hb >> 4, h = hb & 15;
#pragma unroll
  for (int nb = 0; nb < 4; ++nb)
#pragma unroll
    for (int j = 0; j < 4; ++j) {
      int t = q0 + lg * 4 + j;
      O[(size_t)(b * T_ + t) * D_ + h * DH_ + nb * 16 + l15] = f2bf(accO[nb][j] * lj[j]);
    }
}

extern "C" void kernel_launch(void* const* d_in, const int* in_sizes, int n_in,
                              void* d_out, int out_size, void* d_ws, size_t ws_size,
                              hipStream_t stream) {
  const float* x    = (const float*)d_in[0];
  const float* Wqkv = (const float*)d_in[1];
  const float* Wout = (const float*)d_in[2];
  const float* cosT = (const float*)d_in[3];
  const float* sinT = (const float*)d_in[4];
  // d_in[5] = mask (unused; causal handled analytically)
  float* out = (float*)d_out;
  char* ws = (char*)d_ws;
  // ws layout (bytes): 64 MB total
  unsigned short* Xb     = (unsigned short*)(ws);              //  8.0 MB  x bf16 [4096][1024]
  unsigned short* Wqkv_t = (unsigned short*)(ws + 8388608);    //  6.0 MB  Wqkv^T bf16 [3072][1024]
  unsigned short* Wout_t = (unsigned short*)(ws + 14680064);   //  2.0 MB  Wout^T bf16 [1024][1024]
  unsigned short* Ob     = (unsigned short*)(ws + 16777216);   //  8.0 MB  attn out bf16 [4096][1024]
  unsigned short* Qb     = (unsigned short*)(ws + 41943040);   //  8.0 MB  [BH][T][DH]
  unsigned short* Kb     = (unsigned short*)(ws + 50331648);   //  8.0 MB  [BH][T][DH]
  unsigned short* Vt     = (unsigned short*)(ws + 58720256);   //  8.0 MB  [BH][DH][T]

  k_cvt<<<4096, 256, 0, stream>>>(x, Xb);
  k_transpose<<<dim3(48, 16), 256, 0, stream>>>(Wqkv, Wqkv_t, 1024, 3072);
  k_transpose<<<dim3(16, 16), 256, 0, stream>>>(Wout, Wout_t, 1024, 1024);
  k_gemm_qkv_rope<<<dim3(24, 32), 256, 0, stream>>>(Xb, Wqkv_t, cosT, sinT, Qb, Kb, Vt);
  k_attn<<<1024, 256, 0, stream>>>(Qb, Kb, Vt, Ob);
  k_gemm_bt<float><<<dim3(8, 32), 256, 0, stream>>>(Ob, Wout_t, out, 4096, 1024, 1024);
}